// Round 1
// baseline (1455.931 us; speedup 1.0000x reference)
//
#include <hip/hip_runtime.h>
#include <hip/hip_bf16.h>

#define F 128
#define F3 384
#define NRBF 20
#define NITER 3
#define KP 24   // padded filter K: 0..19 phi*fc, 20 fc (bias slot), 21..23 zero
#define EGRID 2048

typedef __hip_bfloat16 bf16;
typedef __bf16 bfrag __attribute__((ext_vector_type(8)));
typedef float f32x4 __attribute__((ext_vector_type(4)));

__device__ __forceinline__ float b2f(bf16 v) { return __bfloat162float(v); }
__device__ __forceinline__ bf16 f2b(float v) { return __float2bfloat16(v); }
__device__ __forceinline__ bfrag ldb(const bf16* p) { return *(const bfrag*)p; }
__device__ __forceinline__ bfrag ldsb(const __bf16* p) { return *(const bfrag*)p; }
__device__ __forceinline__ bfrag cvtf(const float* p) {
    bfrag r;
#pragma unroll
    for (int j = 0; j < 8; ++j) r[j] = (__bf16)p[j];
    return r;
}

// ---------------- dtype detection: bf16 (flag=0) vs f32 (flag=1) ----------------
__global__ void detect_kernel(const unsigned short* __restrict__ raw, int n_u16,
                              int* __restrict__ flag) {
    int i = blockIdx.x * blockDim.x + threadIdx.x;
    int bad = 0;
    for (int k = i; k < n_u16; k += blockDim.x * gridDim.x) {
        unsigned e = (raw[k] >> 7) & 0xFFu;
        if (e >= 140u) bad = 1;
    }
    if (bad) atomicOr(flag, 1);
}

// ---------------- fused param convert: 13 arrays in one launch ----------------
struct CvtArgs {
    const void* src[13];
    float* dst[13];
    int end[14];
};
__global__ void cvt_all_kernel(CvtArgs a, const int* __restrict__ flag, int total) {
    int idx = blockIdx.x * blockDim.x + threadIdx.x;
    if (idx >= total) return;
    int s = 0;
    while (idx >= a.end[s + 1]) ++s;
    int local = idx - a.end[s];
    float v = (*flag) ? ((const float*)a.src[s])[local]
                      : b2f(((const bf16*)a.src[s])[local]);
    a.dst[s][local] = v;
}

// ---------------- fused transpose: 5 weight tensors, f32[NITER][K][Nn]->bf16[NITER][Nn][K] ----
struct TpArgs {
    const float* src[5];
    bf16* dst[5];
    int K[5];
    int Nn[5];
    int end[6];
};
__global__ void tpose_all_kernel(TpArgs a, int total) {
    int idx = blockIdx.x * blockDim.x + threadIdx.x;
    if (idx >= total) return;
    int s = 0;
    while (idx >= a.end[s + 1]) ++s;
    int local = idx - a.end[s];
    int K = a.K[s], Nn = a.Nn[s], slice = K * Nn;
    int t = local / slice, j = local - t * slice;
    int n = j / K, k = j - n * K;
    a.dst[s][local] = f2b(a.src[s][t * slice + k * Nn + n]);
}

// ---------------- fWTf: f32 [NITER][384][24], k=0..19 fW, k=20 fb, rest 0 ----------------
__global__ void fwt_kernel(const float* __restrict__ fW, const float* __restrict__ fb,
                           float* __restrict__ dst, int total) {
    int idx = blockIdx.x * blockDim.x + threadIdx.x;
    if (idx >= total) return;
    int k = idx % KP, rest = idx / KP;
    int n = rest % F3, t = rest / F3;
    float v = (k < NRBF) ? fW[k * (F3 * NITER) + t * F3 + n]
                         : (k == NRBF ? fb[t * F3 + n] : 0.0f);
    dst[idx] = v;
}

// ---------------- geometry -> CSR-slot-ordered edge data ----------------
__global__ void geom_kernel(const float* __restrict__ pos, const int* __restrict__ ii,
                            const int* __restrict__ jj, const int* __restrict__ rank,
                            float* __restrict__ phifc2, float* __restrict__ dir2,
                            int* __restrict__ jj2, int E) {
    int e = blockIdx.x * blockDim.x + threadIdx.x;
    if (e >= E) return;
    int i = ii[e], j = jj[e], l = rank[e];
    float r[3];
#pragma unroll
    for (int d = 0; d < 3; ++d) {
        float v = pos[j * 3 + d] - pos[i * 3 + d];
        if (fabsf(v) < 1e-6f) v = 1e-6f;
        r[d] = v;
    }
    float dd = sqrtf(r[0] * r[0] + r[1] * r[1] + r[2] * r[2]);
    float inv = 1.0f / dd;
    jj2[l] = j;
#pragma unroll
    for (int d = 0; d < 3; ++d) dir2[(size_t)l * 4 + d] = r[d] * inv;
    dir2[(size_t)l * 4 + 3] = 0.0f;
    const float CUT = 5.0f;
    const float PI = 3.14159265358979323846f;
    float fc = (dd < CUT) ? 0.5f * (cosf(PI * dd / CUT) + 1.0f) : 0.0f;
    const float width = CUT / (NRBF - 1);
    const float coeff = -0.5f / (width * width);
    float* pr = phifc2 + (size_t)l * KP;
#pragma unroll
    for (int k = 0; k < NRBF; ++k) {
        float diff = dd - (float)k * width;
        pr[k] = expf(coeff * diff * diff) * fc;
    }
    pr[NRBF] = fc;
    pr[NRBF + 1] = 0.0f;
    pr[NRBF + 2] = 0.0f;
    pr[NRBF + 3] = 0.0f;
}

// ---------------- initial q from embedding ----------------
__global__ void embed_kernel(const int* __restrict__ z, const float* __restrict__ emb,
                             float* __restrict__ q, int N) {
    int idx = blockIdx.x * blockDim.x + threadIdx.x;
    if (idx >= N * F) return;
    int n = idx >> 7, f = idx & 127;
    q[idx] = emb[z[n] * F + f];
}

// ---------------- CSR build ----------------
__global__ void count_kernel(const int* __restrict__ ii, int* __restrict__ counts, int E) {
    int e = blockIdx.x * blockDim.x + threadIdx.x;
    if (e < E) atomicAdd(&counts[ii[e]], 1);
}

__global__ void scan_kernel(const int* __restrict__ counts, int* __restrict__ offs, int N) {
    __shared__ int cum[1024];
    int t = threadIdx.x;
    int chunk = (N + 1023) >> 10;
    int b = t * chunk;
    int e = b + chunk; if (e > N) e = N;
    int s = 0;
    for (int a = b; a < e; ++a) s += counts[a];
    cum[t] = s;
    __syncthreads();
    for (int o = 1; o < 1024; o <<= 1) {
        int u = (t >= o) ? cum[t - o] : 0;
        __syncthreads();
        cum[t] += u;
        __syncthreads();
    }
    int run = cum[t] - s;
    for (int a = b; a < e; ++a) { offs[a] = run; run += counts[a]; }
    if (t == 1023) offs[N] = cum[1023];
}

__global__ void fill_kernel(const int* __restrict__ ii, const int* __restrict__ offs,
                            int* __restrict__ cursor, int* __restrict__ rank, int E) {
    int e = blockIdx.x * blockDim.x + threadIdx.x;
    if (e >= E) return;
    int i = ii[e];
    int p = atomicAdd(&cursor[i], 1);
    rank[e] = offs[i] + p;
}

// ---------------- atom_x via MFMA: X = silu(Q@W1+b1)@W2+b2, 32 atoms/block ----------------
__global__ __launch_bounds__(256) void atom_x_mfma(
    const float* __restrict__ q, const bf16* __restrict__ W1T, const float* __restrict__ b1,
    const bf16* __restrict__ W2T, const float* __restrict__ b2, bf16* __restrict__ x, int N) {
    __shared__ __bf16 H[32][136];
    int tid = threadIdx.x;
    int w = tid >> 6, l = tid & 63;
    int lm = l & 15, q4 = l >> 4;
    int i0 = blockIdx.x * 32;
    f32x4 acc[2][2] = {};
    int r0 = min(i0 + lm, N - 1);
    int r1 = min(i0 + 16 + lm, N - 1);
    for (int kt = 0; kt < 4; ++kt) {
        int ko = kt * 32 + q4 * 8;
        bfrag a0 = cvtf(q + (size_t)r0 * F + ko);
        bfrag a1 = cvtf(q + (size_t)r1 * F + ko);
        bfrag b0 = ldb(W1T + (size_t)(w * 32 + lm) * F + ko);
        bfrag b1f = ldb(W1T + (size_t)(w * 32 + 16 + lm) * F + ko);
        acc[0][0] = __builtin_amdgcn_mfma_f32_16x16x32_bf16(a0, b0, acc[0][0], 0, 0, 0);
        acc[1][0] = __builtin_amdgcn_mfma_f32_16x16x32_bf16(a1, b0, acc[1][0], 0, 0, 0);
        acc[0][1] = __builtin_amdgcn_mfma_f32_16x16x32_bf16(a0, b1f, acc[0][1], 0, 0, 0);
        acc[1][1] = __builtin_amdgcn_mfma_f32_16x16x32_bf16(a1, b1f, acc[1][1], 0, 0, 0);
    }
#pragma unroll
    for (int nt = 0; nt < 2; ++nt) {
        int col = w * 32 + nt * 16 + lm;
        float bb = b1[col];
#pragma unroll
        for (int mt = 0; mt < 2; ++mt)
#pragma unroll
            for (int r = 0; r < 4; ++r) {
                float v = acc[mt][nt][r] + bb;
                H[mt * 16 + q4 * 4 + r][col] = (__bf16)(v / (1.0f + expf(-v)));
            }
    }
    __syncthreads();
#pragma unroll
    for (int j = 0; j < 6; ++j) {
        int n0 = w * 96 + j * 16;
        f32x4 c0 = {}, c1 = {};
        const bf16* bp = W2T + (size_t)(n0 + lm) * F;
        for (int kt = 0; kt < 4; ++kt) {
            int ko = kt * 32 + q4 * 8;
            bfrag a0 = ldsb(&H[lm][ko]);
            bfrag a1 = ldsb(&H[16 + lm][ko]);
            bfrag bf = ldb(bp + ko);
            c0 = __builtin_amdgcn_mfma_f32_16x16x32_bf16(a0, bf, c0, 0, 0, 0);
            c1 = __builtin_amdgcn_mfma_f32_16x16x32_bf16(a1, bf, c1, 0, 0, 0);
        }
        int col = n0 + lm;
        float bb = b2[col];
#pragma unroll
        for (int r = 0; r < 4; ++r) {
            int row0 = i0 + q4 * 4 + r;
            int row1 = row0 + 16;
            if (row0 < N) x[(size_t)row0 * F3 + col] = f2b(c0[r] + bb);
            if (row1 < N) x[(size_t)row1 * F3 + col] = f2b(c1[r] + bb);
        }
    }
}

// ---------------- edge gather v2: persistent blocks + dual-edge pipeline ----------------
// Changes vs edge_gather_pin (R8):
//  (a) persistent blocks: grid=EGRID, each block owns a contiguous chunk of ~13 atoms.
//      The 63-weight register prologue runs 1924x instead of 25000x, and the per-block
//      launch/drain overhead amortizes over the chunk.
//  (b) dual-edge software pipeline: both edges' random x/mu row gathers are issued
//      BEFORE either 21-tap filter dot -> 2x memory-level parallelism per wave; the
//      ~900-cycle HBM gather latency hides under ~130 FMAs of filter math.
//  (c) T0 specialization: at t=0 mu_in==0, so skip the muj gather, the f2 dot, the
//      x[f+256] read, and the mu_in[i] read (-1/3 gather bytes, -1/3 filter FLOPs).
template<int T0>
__global__ __launch_bounds__(128, 2) void edge_gather_p(
    float* __restrict__ q, const bf16* __restrict__ mu_in, const bf16* __restrict__ x,
    const float* __restrict__ phifc2, const float* __restrict__ dir2,
    const int* __restrict__ jj2, const float* __restrict__ fWTf,
    const int* __restrict__ offs, bf16* __restrict__ mu_out, int N, int chunk) {
    int ibeg = blockIdx.x * chunk;
    int iend = min(ibeg + chunk, N);
    if (ibeg >= iend) return;
    int f = threadIdx.x;
    float w0[21], w1[21], w2[21];
    {
        const f32x4* p0 = (const f32x4*)(fWTf + (size_t)f * KP);
        const f32x4* p1 = (const f32x4*)(fWTf + (size_t)(f + 128) * KP);
#pragma unroll
        for (int k = 0; k < 6; ++k) {
            f32x4 t0 = p0[k], t1 = p1[k];
#pragma unroll
            for (int r = 0; r < 4; ++r) {
                int kk = k * 4 + r;
                if (kk < 21) { w0[kk] = t0[r]; w1[kk] = t1[r]; }
            }
        }
        if constexpr (!T0) {
            const f32x4* p2 = (const f32x4*)(fWTf + (size_t)(f + 256) * KP);
#pragma unroll
            for (int k = 0; k < 6; ++k) {
                f32x4 t2 = p2[k];
#pragma unroll
                for (int r = 0; r < 4; ++r) {
                    int kk = k * 4 + r;
                    if (kk < 21) w2[kk] = t2[r];
                }
            }
        }
    }
    // pin: value becomes opaque to the compiler -> cannot rematerialize the load
#pragma unroll
    for (int k = 0; k < 21; ++k) {
        asm volatile("" : "+v"(w0[k]), "+v"(w1[k]));
        if constexpr (!T0) asm volatile("" : "+v"(w2[k]));
    }
    for (int i = ibeg; i < iend; ++i) {
        int beg = offs[i], end = offs[i + 1];
        float accq = 0.0f, am0 = 0.0f, am1 = 0.0f, am2 = 0.0f;
        int l = beg;
        for (; l + 1 < end; l += 2) {
            // --- issue both edges' gathers first (latency-critical path) ---
            int ja = jj2[l], jb = jj2[l + 1];
            const bf16* xja = x + (size_t)ja * F3;
            const bf16* xjb = x + (size_t)jb * F3;
            float xa0 = b2f(xja[f]), xa1 = b2f(xja[f + 128]);
            float xb0 = b2f(xjb[f]), xb1 = b2f(xjb[f + 128]);
            float xa2, xb2, ma0, ma1, ma2, mb0, mb1, mb2;
            if constexpr (!T0) {
                xa2 = b2f(xja[f + 256]);
                xb2 = b2f(xjb[f + 256]);
                const bf16* mja = mu_in + (size_t)ja * F3;
                const bf16* mjb = mu_in + (size_t)jb * F3;
                ma0 = b2f(mja[f]); ma1 = b2f(mja[f + 128]); ma2 = b2f(mja[f + 256]);
                mb0 = b2f(mjb[f]); mb1 = b2f(mjb[f + 128]); mb2 = b2f(mjb[f + 256]);
            }
            f32x4 dva = *(const f32x4*)(dir2 + (size_t)l * 4);
            f32x4 dvb = *(const f32x4*)(dir2 + (size_t)(l + 1) * 4);
            // --- filter dots (phi rows are L1-resident, short latency) ---
            const f32x4* Pa = (const f32x4*)(phifc2 + (size_t)l * KP);
            float f0a = 0.0f, f1a = 0.0f, f2a = 0.0f;
#pragma unroll
            for (int k = 0; k < 6; ++k) {
                f32x4 ph4 = Pa[k];
#pragma unroll
                for (int r = 0; r < 4; ++r) {
                    int kk = k * 4 + r;
                    if (kk < 21) {
                        float ph = ph4[r];
                        f0a += ph * w0[kk];
                        f1a += ph * w1[kk];
                        if constexpr (!T0) f2a += ph * w2[kk];
                    }
                }
            }
            const f32x4* Pb = Pa + 6;
            float f0b = 0.0f, f1b = 0.0f, f2b_ = 0.0f;
#pragma unroll
            for (int k = 0; k < 6; ++k) {
                f32x4 ph4 = Pb[k];
#pragma unroll
                for (int r = 0; r < 4; ++r) {
                    int kk = k * 4 + r;
                    if (kk < 21) {
                        float ph = ph4[r];
                        f0b += ph * w0[kk];
                        f1b += ph * w1[kk];
                        if constexpr (!T0) f2b_ += ph * w2[kk];
                    }
                }
            }
            accq += f0a * xa0 + f0b * xb0;
            float dRa = f1a * xa1, dRb = f1b * xb1;
            am0 += dRa * dva[0] + dRb * dvb[0];
            am1 += dRa * dva[1] + dRb * dvb[1];
            am2 += dRa * dva[2] + dRb * dvb[2];
            if constexpr (!T0) {
                float dMa = f2a * xa2, dMb = f2b_ * xb2;
                am0 += dMa * ma0 + dMb * mb0;
                am1 += dMa * ma1 + dMb * mb1;
                am2 += dMa * ma2 + dMb * mb2;
            }
        }
        if (l < end) {
            int ja = jj2[l];
            const bf16* xja = x + (size_t)ja * F3;
            float xa0 = b2f(xja[f]), xa1 = b2f(xja[f + 128]);
            float xa2, ma0, ma1, ma2;
            if constexpr (!T0) {
                xa2 = b2f(xja[f + 256]);
                const bf16* mja = mu_in + (size_t)ja * F3;
                ma0 = b2f(mja[f]); ma1 = b2f(mja[f + 128]); ma2 = b2f(mja[f + 256]);
            }
            f32x4 dva = *(const f32x4*)(dir2 + (size_t)l * 4);
            const f32x4* Pa = (const f32x4*)(phifc2 + (size_t)l * KP);
            float f0a = 0.0f, f1a = 0.0f, f2a = 0.0f;
#pragma unroll
            for (int k = 0; k < 6; ++k) {
                f32x4 ph4 = Pa[k];
#pragma unroll
                for (int r = 0; r < 4; ++r) {
                    int kk = k * 4 + r;
                    if (kk < 21) {
                        float ph = ph4[r];
                        f0a += ph * w0[kk];
                        f1a += ph * w1[kk];
                        if constexpr (!T0) f2a += ph * w2[kk];
                    }
                }
            }
            accq += f0a * xa0;
            float dRa = f1a * xa1;
            am0 += dRa * dva[0];
            am1 += dRa * dva[1];
            am2 += dRa * dva[2];
            if constexpr (!T0) {
                float dMa = f2a * xa2;
                am0 += dMa * ma0;
                am1 += dMa * ma1;
                am2 += dMa * ma2;
            }
        }
        q[(size_t)i * F + f] += accq;
        size_t mb_ = (size_t)i * F3 + f;
        if constexpr (T0) {
            mu_out[mb_]       = f2b(am0);
            mu_out[mb_ + 128] = f2b(am1);
            mu_out[mb_ + 256] = f2b(am2);
        } else {
            mu_out[mb_]       = f2b(b2f(mu_in[mb_]) + am0);
            mu_out[mb_ + 128] = f2b(b2f(mu_in[mb_ + 128]) + am1);
            mu_out[mb_ + 256] = f2b(b2f(mu_in[mb_ + 256]) + am2);
        }
    }
}

// ---------------- mixing via MFMA, 16 atoms/block ----------------
__global__ __launch_bounds__(256) void mix_mfma(
    float* __restrict__ q, bf16* __restrict__ mu,
    const bf16* __restrict__ WmixT, const bf16* __restrict__ W1T, const float* __restrict__ b1,
    const bf16* __restrict__ W2T, const float* __restrict__ b2, int N) {
    __shared__ __bf16 MM[48][264];
    __shared__ __bf16 CT[16][264];
    __shared__ __bf16 HM[16][136];
    __shared__ __bf16 Y[16][392];
    int tid = threadIdx.x;
    int w = tid >> 6, l = tid & 63;
    int lm = l & 15, q4 = l >> 4;
    int i0 = blockIdx.x * 16;
    int rowsM = N * 3;
    {
        f32x4 acc[3][4] = {};
        int mr[3];
#pragma unroll
        for (int mt = 0; mt < 3; ++mt) mr[mt] = min(i0 * 3 + mt * 16 + lm, rowsM - 1);
        for (int kt = 0; kt < 4; ++kt) {
            int ko = kt * 32 + q4 * 8;
            bfrag a[3], b[4];
#pragma unroll
            for (int mt = 0; mt < 3; ++mt) a[mt] = ldb(mu + (size_t)mr[mt] * F + ko);
#pragma unroll
            for (int nt = 0; nt < 4; ++nt)
                b[nt] = ldb(WmixT + (size_t)(w * 64 + nt * 16 + lm) * F + ko);
#pragma unroll
            for (int mt = 0; mt < 3; ++mt)
#pragma unroll
                for (int nt = 0; nt < 4; ++nt)
                    acc[mt][nt] = __builtin_amdgcn_mfma_f32_16x16x32_bf16(a[mt], b[nt], acc[mt][nt], 0, 0, 0);
        }
#pragma unroll
        for (int mt = 0; mt < 3; ++mt)
#pragma unroll
            for (int nt = 0; nt < 4; ++nt)
#pragma unroll
                for (int r = 0; r < 4; ++r)
                    MM[mt * 16 + q4 * 4 + r][w * 64 + nt * 16 + lm] = (__bf16)acc[mt][nt][r];
    }
    __syncthreads();
    for (int idx = tid; idx < 16 * F; idx += 256) {
        int a = idx >> 7, f = idx & 127;
        int i = min(i0 + a, N - 1);
        float v0 = (float)MM[a * 3 + 0][f];
        float v1 = (float)MM[a * 3 + 1][f];
        float v2 = (float)MM[a * 3 + 2][f];
        CT[a][f] = (__bf16)q[(size_t)i * F + f];
        CT[a][F + f] = (__bf16)sqrtf(v0 * v0 + v1 * v1 + v2 * v2 + 1e-8f);
    }
    __syncthreads();
    {
        f32x4 c[2] = {};
        for (int kt = 0; kt < 8; ++kt) {
            int ko = kt * 32 + q4 * 8;
            bfrag a = ldsb(&CT[lm][ko]);
#pragma unroll
            for (int nt = 0; nt < 2; ++nt) {
                bfrag b = ldb(W1T + (size_t)(w * 32 + nt * 16 + lm) * 256 + ko);
                c[nt] = __builtin_amdgcn_mfma_f32_16x16x32_bf16(a, b, c[nt], 0, 0, 0);
            }
        }
#pragma unroll
        for (int nt = 0; nt < 2; ++nt) {
            int col = w * 32 + nt * 16 + lm;
            float bb = b1[col];
#pragma unroll
            for (int r = 0; r < 4; ++r) {
                float v = c[nt][r] + bb;
                HM[q4 * 4 + r][col] = (__bf16)(v / (1.0f + expf(-v)));
            }
        }
    }
    __syncthreads();
#pragma unroll
    for (int j = 0; j < 6; ++j) {
        int n0 = w * 96 + j * 16;
        f32x4 c = {};
        const bf16* bp = W2T + (size_t)(n0 + lm) * F;
        for (int kt = 0; kt < 4; ++kt) {
            int ko = kt * 32 + q4 * 8;
            bfrag a = ldsb(&HM[lm][ko]);
            bfrag b = ldb(bp + ko);
            c = __builtin_amdgcn_mfma_f32_16x16x32_bf16(a, b, c, 0, 0, 0);
        }
        int col = n0 + lm;
        float bb = b2[col];
#pragma unroll
        for (int r = 0; r < 4; ++r)
            Y[q4 * 4 + r][col] = (__bf16)(c[r] + bb);
    }
    __syncthreads();
    for (int idx = tid; idx < 16 * F; idx += 256) {
        int a = idx >> 7, f = idx & 127;
        int i = i0 + a;
        if (i >= N) continue;
        float V0 = (float)MM[a * 3 + 0][f], W0 = (float)MM[a * 3 + 0][F + f];
        float V1 = (float)MM[a * 3 + 1][f], W1v = (float)MM[a * 3 + 1][F + f];
        float V2 = (float)MM[a * 3 + 2][f], W2v = (float)MM[a * 3 + 2][F + f];
        float s = V0 * W0 + V1 * W1v + V2 * W2v;
        float yq = (float)Y[a][f], ym = (float)Y[a][F + f], ys = (float)Y[a][2 * F + f];
        q[(size_t)i * F + f] += yq + ys * s;
        size_t mb = (size_t)i * F3 + f;
        mu[mb]       = f2b(b2f(mu[mb]) + ym * W0);
        mu[mb + 128] = f2b(b2f(mu[mb + 128]) + ym * W1v);
        mu[mb + 256] = f2b(b2f(mu[mb + 256]) + ym * W2v);
    }
}

// ---------------- output: q ‖ mu, dtype per flag ----------------
__global__ void out_kernel(const float* __restrict__ q, const bf16* __restrict__ mu,
                           void* __restrict__ out, int N, const int* __restrict__ flag) {
    int idx = blockIdx.x * blockDim.x + threadIdx.x;
    int nq = N * F;
    int tot = nq + N * F3;
    if (idx >= tot) return;
    float v = (idx < nq) ? q[idx] : b2f(mu[idx - nq]);
    if (*flag) ((float*)out)[idx] = v;
    else       ((bf16*)out)[idx] = f2b(v);
}

extern "C" void kernel_launch(void* const* d_in, const int* in_sizes, int n_in,
                              void* d_out, int out_size, void* d_ws, size_t ws_size,
                              hipStream_t stream) {
    const int* z = (const int*)d_in[0];
    const int* idx_i = (const int*)d_in[2];
    const int* idx_j = (const int*)d_in[3];

    int N = in_sizes[0];
    int E = in_sizes[2];

    char* base = (char*)d_ws;
    size_t off = 0;
    auto alloc = [&](size_t bytes) -> void* {
        void* p = base + off;
        off += (bytes + 255) & ~(size_t)255;
        return p;
    };

    int* flag = (int*)alloc(4);
    float* pos_f = (float*)alloc((size_t)in_sizes[1] * 4);
    float* emb_f = (float*)alloc((size_t)in_sizes[4] * 4);
    float* fW_f = (float*)alloc((size_t)in_sizes[5] * 4);
    float* fb_f = (float*)alloc((size_t)in_sizes[6] * 4);
    float* iW1_f = (float*)alloc((size_t)in_sizes[7] * 4);
    float* ib1_f = (float*)alloc((size_t)in_sizes[8] * 4);
    float* iW2_f = (float*)alloc((size_t)in_sizes[9] * 4);
    float* ib2_f = (float*)alloc((size_t)in_sizes[10] * 4);
    float* mWmix_f = (float*)alloc((size_t)in_sizes[11] * 4);
    float* mW1_f = (float*)alloc((size_t)in_sizes[12] * 4);
    float* mb1_f = (float*)alloc((size_t)in_sizes[13] * 4);
    float* mW2_f = (float*)alloc((size_t)in_sizes[14] * 4);
    float* mb2_f = (float*)alloc((size_t)in_sizes[15] * 4);
    bf16* iW1T = (bf16*)alloc((size_t)NITER * F * F * 2);
    bf16* iW2T = (bf16*)alloc((size_t)NITER * F3 * F * 2);
    bf16* mWmixT = (bf16*)alloc((size_t)NITER * 2 * F * F * 2);
    bf16* mW1T = (bf16*)alloc((size_t)NITER * F * 2 * F * 2);
    bf16* mW2T = (bf16*)alloc((size_t)NITER * F3 * F * 2);
    float* fWTf = (float*)alloc((size_t)NITER * F3 * KP * 4);
    float* q = (float*)alloc((size_t)N * F * 4);
    bf16* mua = (bf16*)alloc((size_t)N * F3 * 2);
    bf16* mub = (bf16*)alloc((size_t)N * F3 * 2);
    bf16* xbuf = (bf16*)alloc((size_t)N * F3 * 2);
    float* phifc2 = (float*)alloc((size_t)(E + 16) * KP * 4);
    float* dir2 = (float*)alloc((size_t)(E + 16) * 4 * 4);
    int* jj2 = (int*)alloc((size_t)(E + 16) * 4);
    int* rank = (int*)alloc((size_t)E * 4);
    int* counts = (int*)alloc((size_t)N * 4);
    int* offs = (int*)alloc((size_t)(N + 1) * 4);

    hipMemsetAsync(flag, 0, 4, stream);
    detect_kernel<<<64, 256, 0, stream>>>((const unsigned short*)d_in[1], in_sizes[1], flag);

    {
        CvtArgs a;
        const int srcIdx[13] = {1, 4, 5, 6, 7, 8, 9, 10, 11, 12, 13, 14, 15};
        float* dsts[13] = {pos_f, emb_f, fW_f, fb_f, iW1_f, ib1_f, iW2_f, ib2_f,
                           mWmix_f, mW1_f, mb1_f, mW2_f, mb2_f};
        int cum = 0;
        a.end[0] = 0;
        for (int s = 0; s < 13; ++s) {
            a.src[s] = d_in[srcIdx[s]];
            a.dst[s] = dsts[s];
            cum += in_sizes[srcIdx[s]];
            a.end[s + 1] = cum;
        }
        cvt_all_kernel<<<(cum + 255) / 256, 256, 0, stream>>>(a, flag, cum);
    }

    {
        TpArgs a;
        const float* srcs[5] = {iW1_f, iW2_f, mWmix_f, mW1_f, mW2_f};
        bf16* dsts[5] = {iW1T, iW2T, mWmixT, mW1T, mW2T};
        int Ks[5] = {F, F, F, 2 * F, F};
        int Nns[5] = {F, F3, 2 * F, F, F3};
        int cum = 0;
        a.end[0] = 0;
        for (int s = 0; s < 5; ++s) {
            a.src[s] = srcs[s];
            a.dst[s] = dsts[s];
            a.K[s] = Ks[s];
            a.Nn[s] = Nns[s];
            cum += NITER * Ks[s] * Nns[s];
            a.end[s + 1] = cum;
        }
        tpose_all_kernel<<<(cum + 255) / 256, 256, 0, stream>>>(a, cum);
    }
    {
        int total = NITER * F3 * KP;
        fwt_kernel<<<(total + 255) / 256, 256, 0, stream>>>(fW_f, fb_f, fWTf, total);
    }

    // CSR build (rank needed by geom)
    hipMemsetAsync(counts, 0, (size_t)N * 4, stream);
    count_kernel<<<(E + 255) / 256, 256, 0, stream>>>(idx_i, counts, E);
    scan_kernel<<<1, 1024, 0, stream>>>(counts, offs, N);
    hipMemsetAsync(counts, 0, (size_t)N * 4, stream);
    fill_kernel<<<(E + 255) / 256, 256, 0, stream>>>(idx_i, offs, counts, rank, E);

    geom_kernel<<<(E + 255) / 256, 256, 0, stream>>>(pos_f, idx_i, idx_j, rank,
                                                     phifc2, dir2, jj2, E);
    embed_kernel<<<(N * F + 255) / 256, 256, 0, stream>>>(z, emb_f, q, N);
    hipMemsetAsync(mua, 0, (size_t)N * F3 * 2, stream);

    int chunk = (N + EGRID - 1) / EGRID;
    bf16* muin = mua;
    bf16* muout = mub;
    for (int t = 0; t < NITER; ++t) {
        atom_x_mfma<<<(N + 31) / 32, 256, 0, stream>>>(q, iW1T + (size_t)t * F * F, ib1_f + t * F,
                                                       iW2T + (size_t)t * F3 * F, ib2_f + t * F3,
                                                       xbuf, N);
        if (t == 0)
            edge_gather_p<1><<<EGRID, 128, 0, stream>>>(q, muin, xbuf, phifc2, dir2, jj2,
                                                        fWTf + (size_t)t * F3 * KP, offs, muout,
                                                        N, chunk);
        else
            edge_gather_p<0><<<EGRID, 128, 0, stream>>>(q, muin, xbuf, phifc2, dir2, jj2,
                                                        fWTf + (size_t)t * F3 * KP, offs, muout,
                                                        N, chunk);
        mix_mfma<<<(N + 15) / 16, 256, 0, stream>>>(q, muout, mWmixT + (size_t)t * 2 * F * F,
                                                    mW1T + (size_t)t * F * 2 * F, mb1_f + t * F,
                                                    mW2T + (size_t)t * F3 * F, mb2_f + t * F3, N);
        bf16* tm = muin; muin = muout; muout = tm;
    }

    int tot = N * (F + F3);
    out_kernel<<<(tot + 255) / 256, 256, 0, stream>>>(q, muin, d_out, N, flag);
}

// Round 2
// 850.702 us; speedup vs baseline: 1.7114x; 1.7114x over previous
//
#include <hip/hip_runtime.h>
#include <hip/hip_bf16.h>

#define F 128
#define F3 384
#define NRBF 20
#define NITER 3
#define KP 24   // padded filter K: 0..19 phi*fc, 20 fc (bias slot), 21..23 zero

typedef __hip_bfloat16 bf16;
typedef __bf16 bfrag __attribute__((ext_vector_type(8)));
typedef float f32x4 __attribute__((ext_vector_type(4)));
typedef unsigned short u16x4 __attribute__((ext_vector_type(4)));

__device__ __forceinline__ float b2f(bf16 v) { return __bfloat162float(v); }
__device__ __forceinline__ bf16 f2b(float v) { return __float2bfloat16(v); }
__device__ __forceinline__ bfrag ldb(const bf16* p) { return *(const bfrag*)p; }
__device__ __forceinline__ bfrag ldsb(const __bf16* p) { return *(const bfrag*)p; }
__device__ __forceinline__ float u2f(unsigned short u) {
    union { float f; unsigned int i; } c;
    c.i = (unsigned int)u << 16;
    return c.f;
}
__device__ __forceinline__ unsigned short f2u(float v) {
    bf16 b = f2b(v);
    unsigned short u;
    __builtin_memcpy(&u, &b, 2);
    return u;
}
__device__ __forceinline__ unsigned short bb2u(__bf16 v) {
    unsigned short u;
    __builtin_memcpy(&u, &v, 2);
    return u;
}
__device__ __forceinline__ bfrag cvtf(const float* p) {
    bfrag r;
#pragma unroll
    for (int j = 0; j < 8; ++j) r[j] = (__bf16)p[j];
    return r;
}

// ---------------- dtype detection: bf16 (flag=0) vs f32 (flag=1) ----------------
__global__ void detect_kernel(const unsigned short* __restrict__ raw, int n_u16,
                              int* __restrict__ flag) {
    int i = blockIdx.x * blockDim.x + threadIdx.x;
    int bad = 0;
    for (int k = i; k < n_u16; k += blockDim.x * gridDim.x) {
        unsigned e = (raw[k] >> 7) & 0xFFu;
        if (e >= 140u) bad = 1;
    }
    if (bad) atomicOr(flag, 1);
}

// ---------------- fused param convert: 13 arrays in one launch ----------------
struct CvtArgs {
    const void* src[13];
    float* dst[13];
    int end[14];
};
__global__ void cvt_all_kernel(CvtArgs a, const int* __restrict__ flag, int total) {
    int idx = blockIdx.x * blockDim.x + threadIdx.x;
    if (idx >= total) return;
    int s = 0;
    while (idx >= a.end[s + 1]) ++s;
    int local = idx - a.end[s];
    float v = (*flag) ? ((const float*)a.src[s])[local]
                      : b2f(((const bf16*)a.src[s])[local]);
    a.dst[s][local] = v;
}

// ---------------- fused transpose: 5 weight tensors, f32[NITER][K][Nn]->bf16[NITER][Nn][K] ----
struct TpArgs {
    const float* src[5];
    bf16* dst[5];
    int K[5];
    int Nn[5];
    int end[6];
};
__global__ void tpose_all_kernel(TpArgs a, int total) {
    int idx = blockIdx.x * blockDim.x + threadIdx.x;
    if (idx >= total) return;
    int s = 0;
    while (idx >= a.end[s + 1]) ++s;
    int local = idx - a.end[s];
    int K = a.K[s], Nn = a.Nn[s], slice = K * Nn;
    int t = local / slice, j = local - t * slice;
    int n = j / K, k = j - n * K;
    a.dst[s][local] = f2b(a.src[s][t * slice + k * Nn + n]);
}

// ---------------- fWTf: f32 [NITER][384][24], k=0..19 fW, k=20 fb, rest 0 ----------------
__global__ void fwt_kernel(const float* __restrict__ fW, const float* __restrict__ fb,
                           float* __restrict__ dst, int total) {
    int idx = blockIdx.x * blockDim.x + threadIdx.x;
    if (idx >= total) return;
    int k = idx % KP, rest = idx / KP;
    int n = rest % F3, t = rest / F3;
    float v = (k < NRBF) ? fW[k * (F3 * NITER) + t * F3 + n]
                         : (k == NRBF ? fb[t * F3 + n] : 0.0f);
    dst[idx] = v;
}

// ---------------- geometry -> CSR-slot-ordered edge data ----------------
__global__ void geom_kernel(const float* __restrict__ pos, const int* __restrict__ ii,
                            const int* __restrict__ jj, const int* __restrict__ rank,
                            float* __restrict__ phifc2, float* __restrict__ dir2,
                            int* __restrict__ jj2, int E) {
    int e = blockIdx.x * blockDim.x + threadIdx.x;
    if (e >= E) return;
    int i = ii[e], j = jj[e], l = rank[e];
    float r[3];
#pragma unroll
    for (int d = 0; d < 3; ++d) {
        float v = pos[j * 3 + d] - pos[i * 3 + d];
        if (fabsf(v) < 1e-6f) v = 1e-6f;
        r[d] = v;
    }
    float dd = sqrtf(r[0] * r[0] + r[1] * r[1] + r[2] * r[2]);
    float inv = 1.0f / dd;
    jj2[l] = j;
#pragma unroll
    for (int d = 0; d < 3; ++d) dir2[(size_t)l * 4 + d] = r[d] * inv;
    dir2[(size_t)l * 4 + 3] = 0.0f;
    const float CUT = 5.0f;
    const float PI = 3.14159265358979323846f;
    float fc = (dd < CUT) ? 0.5f * (cosf(PI * dd / CUT) + 1.0f) : 0.0f;
    const float width = CUT / (NRBF - 1);
    const float coeff = -0.5f / (width * width);
    float* pr = phifc2 + (size_t)l * KP;
#pragma unroll
    for (int k = 0; k < NRBF; ++k) {
        float diff = dd - (float)k * width;
        pr[k] = expf(coeff * diff * diff) * fc;
    }
    pr[NRBF] = fc;
    pr[NRBF + 1] = 0.0f;
    pr[NRBF + 2] = 0.0f;
    pr[NRBF + 3] = 0.0f;
}

// ---------------- initial q from embedding ----------------
__global__ void embed_kernel(const int* __restrict__ z, const float* __restrict__ emb,
                             float* __restrict__ q, int N) {
    int idx = blockIdx.x * blockDim.x + threadIdx.x;
    if (idx >= N * F) return;
    int n = idx >> 7, f = idx & 127;
    q[idx] = emb[z[n] * F + f];
}

// ---------------- CSR build ----------------
__global__ void count_kernel(const int* __restrict__ ii, int* __restrict__ counts, int E) {
    int e = blockIdx.x * blockDim.x + threadIdx.x;
    if (e < E) atomicAdd(&counts[ii[e]], 1);
}

__global__ void scan_kernel(const int* __restrict__ counts, int* __restrict__ offs, int N) {
    __shared__ int cum[1024];
    int t = threadIdx.x;
    int chunk = (N + 1023) >> 10;
    int b = t * chunk;
    int e = b + chunk; if (e > N) e = N;
    int s = 0;
    for (int a = b; a < e; ++a) s += counts[a];
    cum[t] = s;
    __syncthreads();
    for (int o = 1; o < 1024; o <<= 1) {
        int u = (t >= o) ? cum[t - o] : 0;
        __syncthreads();
        cum[t] += u;
        __syncthreads();
    }
    int run = cum[t] - s;
    for (int a = b; a < e; ++a) { offs[a] = run; run += counts[a]; }
    if (t == 1023) offs[N] = cum[1023];
}

__global__ void fill_kernel(const int* __restrict__ ii, const int* __restrict__ offs,
                            int* __restrict__ cursor, int* __restrict__ rank, int E) {
    int e = blockIdx.x * blockDim.x + threadIdx.x;
    if (e >= E) return;
    int i = ii[e];
    int p = atomicAdd(&cursor[i], 1);
    rank[e] = offs[i] + p;
}

// ---------------- atom_x via MFMA: X = silu(Q@W1+b1)@W2+b2, 32 atoms/block ----------------
// Output written in PACKED layout xp[N][128][4] bf16 (comp 0..2, pad) so the edge
// gather reads one 8B word per edge instead of 3 strided 2B loads. Second-GEMM
// results stage through LDS (XS) to keep the global write coalesced.
__global__ __launch_bounds__(256) void atom_x_mfma(
    const float* __restrict__ q, const bf16* __restrict__ W1T, const float* __restrict__ b1,
    const bf16* __restrict__ W2T, const float* __restrict__ b2, bf16* __restrict__ xp, int N) {
    __shared__ __bf16 H[32][136];
    __shared__ __bf16 XS[32][392];
    int tid = threadIdx.x;
    int w = tid >> 6, l = tid & 63;
    int lm = l & 15, q4 = l >> 4;
    int i0 = blockIdx.x * 32;
    f32x4 acc[2][2] = {};
    int r0 = min(i0 + lm, N - 1);
    int r1 = min(i0 + 16 + lm, N - 1);
    for (int kt = 0; kt < 4; ++kt) {
        int ko = kt * 32 + q4 * 8;
        bfrag a0 = cvtf(q + (size_t)r0 * F + ko);
        bfrag a1 = cvtf(q + (size_t)r1 * F + ko);
        bfrag b0 = ldb(W1T + (size_t)(w * 32 + lm) * F + ko);
        bfrag b1f = ldb(W1T + (size_t)(w * 32 + 16 + lm) * F + ko);
        acc[0][0] = __builtin_amdgcn_mfma_f32_16x16x32_bf16(a0, b0, acc[0][0], 0, 0, 0);
        acc[1][0] = __builtin_amdgcn_mfma_f32_16x16x32_bf16(a1, b0, acc[1][0], 0, 0, 0);
        acc[0][1] = __builtin_amdgcn_mfma_f32_16x16x32_bf16(a0, b1f, acc[0][1], 0, 0, 0);
        acc[1][1] = __builtin_amdgcn_mfma_f32_16x16x32_bf16(a1, b1f, acc[1][1], 0, 0, 0);
    }
#pragma unroll
    for (int nt = 0; nt < 2; ++nt) {
        int col = w * 32 + nt * 16 + lm;
        float bb = b1[col];
#pragma unroll
        for (int mt = 0; mt < 2; ++mt)
#pragma unroll
            for (int r = 0; r < 4; ++r) {
                float v = acc[mt][nt][r] + bb;
                H[mt * 16 + q4 * 4 + r][col] = (__bf16)(v / (1.0f + expf(-v)));
            }
    }
    __syncthreads();
#pragma unroll
    for (int j = 0; j < 6; ++j) {
        int n0 = w * 96 + j * 16;
        f32x4 c0 = {}, c1 = {};
        const bf16* bp = W2T + (size_t)(n0 + lm) * F;
        for (int kt = 0; kt < 4; ++kt) {
            int ko = kt * 32 + q4 * 8;
            bfrag a0 = ldsb(&H[lm][ko]);
            bfrag a1 = ldsb(&H[16 + lm][ko]);
            bfrag bf = ldb(bp + ko);
            c0 = __builtin_amdgcn_mfma_f32_16x16x32_bf16(a0, bf, c0, 0, 0, 0);
            c1 = __builtin_amdgcn_mfma_f32_16x16x32_bf16(a1, bf, c1, 0, 0, 0);
        }
        int col = n0 + lm;
        float bb = b2[col];
#pragma unroll
        for (int r = 0; r < 4; ++r) {
            XS[q4 * 4 + r][col] = (__bf16)(c0[r] + bb);
            XS[16 + q4 * 4 + r][col] = (__bf16)(c1[r] + bb);
        }
    }
    __syncthreads();
    for (int idx = tid; idx < 32 * F; idx += 256) {
        int a = idx >> 7, f = idx & 127;
        int row = i0 + a;
        if (row >= N) continue;
        u16x4 pv;
        pv[0] = bb2u(XS[a][f]);
        pv[1] = bb2u(XS[a][f + 128]);
        pv[2] = bb2u(XS[a][f + 256]);
        pv[3] = 0;
        *(u16x4*)(xp + (size_t)row * 512 + f * 4) = pv;
    }
}

// ---------------- edge gather v3: grid=N (proven latency-hiding structure) ----------------
// vs R0's 115us edge_gather_pin: (a) packed 8B gathers from xp/mup instead of 6x 2B
// strided loads (fewer transactions + less address VALU), (b) dual-edge in-flight
// pipeline within the per-atom loop, (c) T0 specialization (mu==0 at t=0).
template<int T0>
__global__ __launch_bounds__(128, 2) void edge_gather_v3(
    float* __restrict__ q, const bf16* __restrict__ mu_in, const bf16* __restrict__ xp,
    const bf16* __restrict__ mup,
    const float* __restrict__ phifc2, const float* __restrict__ dir2,
    const int* __restrict__ jj2, const float* __restrict__ fWTf,
    const int* __restrict__ offs, bf16* __restrict__ mu_out, int N) {
    int i = blockIdx.x;
    int f = threadIdx.x;
    float w0[21], w1[21], w2[21];
    {
        const f32x4* p0 = (const f32x4*)(fWTf + (size_t)f * KP);
        const f32x4* p1 = (const f32x4*)(fWTf + (size_t)(f + 128) * KP);
#pragma unroll
        for (int k = 0; k < 6; ++k) {
            f32x4 t0 = p0[k], t1 = p1[k];
#pragma unroll
            for (int r = 0; r < 4; ++r) {
                int kk = k * 4 + r;
                if (kk < 21) { w0[kk] = t0[r]; w1[kk] = t1[r]; }
            }
        }
        if constexpr (!T0) {
            const f32x4* p2 = (const f32x4*)(fWTf + (size_t)(f + 256) * KP);
#pragma unroll
            for (int k = 0; k < 6; ++k) {
                f32x4 t2 = p2[k];
#pragma unroll
                for (int r = 0; r < 4; ++r) {
                    int kk = k * 4 + r;
                    if (kk < 21) w2[kk] = t2[r];
                }
            }
        }
    }
    // pin: value becomes opaque to the compiler -> cannot rematerialize the load
#pragma unroll
    for (int k = 0; k < 21; ++k) {
        asm volatile("" : "+v"(w0[k]), "+v"(w1[k]));
        if constexpr (!T0) asm volatile("" : "+v"(w2[k]));
    }
    int beg = offs[i], end = offs[i + 1];
    float accq = 0.0f, am0 = 0.0f, am1 = 0.0f, am2 = 0.0f;
    int l = beg;
    for (; l + 1 < end; l += 2) {
        // --- issue both edges' gathers first (latency-critical path) ---
        int ja = jj2[l], jb = jj2[l + 1];
        u16x4 xa = *(const u16x4*)(xp + (size_t)ja * 512 + f * 4);
        u16x4 xb = *(const u16x4*)(xp + (size_t)jb * 512 + f * 4);
        u16x4 ma, mb2v;
        if constexpr (!T0) {
            ma = *(const u16x4*)(mup + (size_t)ja * 512 + f * 4);
            mb2v = *(const u16x4*)(mup + (size_t)jb * 512 + f * 4);
        }
        f32x4 dva = *(const f32x4*)(dir2 + (size_t)l * 4);
        f32x4 dvb = *(const f32x4*)(dir2 + (size_t)(l + 1) * 4);
        // --- filter dots (phi rows stream through L1/L2, short latency) ---
        const f32x4* Pa = (const f32x4*)(phifc2 + (size_t)l * KP);
        float f0a = 0.0f, f1a = 0.0f, f2a = 0.0f;
#pragma unroll
        for (int k = 0; k < 6; ++k) {
            f32x4 ph4 = Pa[k];
#pragma unroll
            for (int r = 0; r < 4; ++r) {
                int kk = k * 4 + r;
                if (kk < 21) {
                    float ph = ph4[r];
                    f0a += ph * w0[kk];
                    f1a += ph * w1[kk];
                    if constexpr (!T0) f2a += ph * w2[kk];
                }
            }
        }
        const f32x4* Pb = Pa + 6;
        float f0b = 0.0f, f1b = 0.0f, f2b_ = 0.0f;
#pragma unroll
        for (int k = 0; k < 6; ++k) {
            f32x4 ph4 = Pb[k];
#pragma unroll
            for (int r = 0; r < 4; ++r) {
                int kk = k * 4 + r;
                if (kk < 21) {
                    float ph = ph4[r];
                    f0b += ph * w0[kk];
                    f1b += ph * w1[kk];
                    if constexpr (!T0) f2b_ += ph * w2[kk];
                }
            }
        }
        accq += f0a * u2f(xa[0]) + f0b * u2f(xb[0]);
        float dRa = f1a * u2f(xa[1]), dRb = f1b * u2f(xb[1]);
        am0 += dRa * dva[0] + dRb * dvb[0];
        am1 += dRa * dva[1] + dRb * dvb[1];
        am2 += dRa * dva[2] + dRb * dvb[2];
        if constexpr (!T0) {
            float dMa = f2a * u2f(xa[2]), dMb = f2b_ * u2f(xb[2]);
            am0 += dMa * u2f(ma[0]) + dMb * u2f(mb2v[0]);
            am1 += dMa * u2f(ma[1]) + dMb * u2f(mb2v[1]);
            am2 += dMa * u2f(ma[2]) + dMb * u2f(mb2v[2]);
        }
    }
    if (l < end) {
        int ja = jj2[l];
        u16x4 xa = *(const u16x4*)(xp + (size_t)ja * 512 + f * 4);
        u16x4 ma;
        if constexpr (!T0) ma = *(const u16x4*)(mup + (size_t)ja * 512 + f * 4);
        f32x4 dva = *(const f32x4*)(dir2 + (size_t)l * 4);
        const f32x4* Pa = (const f32x4*)(phifc2 + (size_t)l * KP);
        float f0a = 0.0f, f1a = 0.0f, f2a = 0.0f;
#pragma unroll
        for (int k = 0; k < 6; ++k) {
            f32x4 ph4 = Pa[k];
#pragma unroll
            for (int r = 0; r < 4; ++r) {
                int kk = k * 4 + r;
                if (kk < 21) {
                    float ph = ph4[r];
                    f0a += ph * w0[kk];
                    f1a += ph * w1[kk];
                    if constexpr (!T0) f2a += ph * w2[kk];
                }
            }
        }
        accq += f0a * u2f(xa[0]);
        float dRa = f1a * u2f(xa[1]);
        am0 += dRa * dva[0];
        am1 += dRa * dva[1];
        am2 += dRa * dva[2];
        if constexpr (!T0) {
            float dMa = f2a * u2f(xa[2]);
            am0 += dMa * u2f(ma[0]);
            am1 += dMa * u2f(ma[1]);
            am2 += dMa * u2f(ma[2]);
        }
    }
    q[(size_t)i * F + f] += accq;
    size_t mb_ = (size_t)i * F3 + f;
    if constexpr (T0) {
        mu_out[mb_]       = f2b(am0);
        mu_out[mb_ + 128] = f2b(am1);
        mu_out[mb_ + 256] = f2b(am2);
    } else {
        mu_out[mb_]       = f2b(b2f(mu_in[mb_]) + am0);
        mu_out[mb_ + 128] = f2b(b2f(mu_in[mb_ + 128]) + am1);
        mu_out[mb_ + 256] = f2b(b2f(mu_in[mb_ + 256]) + am2);
    }
}

// ---------------- mixing via MFMA, 16 atoms/block ----------------
// Also emits the PACKED mu copy (mup) consumed by next iteration's edge gather.
__global__ __launch_bounds__(256) void mix_mfma(
    float* __restrict__ q, bf16* __restrict__ mu,
    const bf16* __restrict__ WmixT, const bf16* __restrict__ W1T, const float* __restrict__ b1,
    const bf16* __restrict__ W2T, const float* __restrict__ b2,
    bf16* __restrict__ mup, int wp, int N) {
    __shared__ __bf16 MM[48][264];
    __shared__ __bf16 CT[16][264];
    __shared__ __bf16 HM[16][136];
    __shared__ __bf16 Y[16][392];
    int tid = threadIdx.x;
    int w = tid >> 6, l = tid & 63;
    int lm = l & 15, q4 = l >> 4;
    int i0 = blockIdx.x * 16;
    int rowsM = N * 3;
    {
        f32x4 acc[3][4] = {};
        int mr[3];
#pragma unroll
        for (int mt = 0; mt < 3; ++mt) mr[mt] = min(i0 * 3 + mt * 16 + lm, rowsM - 1);
        for (int kt = 0; kt < 4; ++kt) {
            int ko = kt * 32 + q4 * 8;
            bfrag a[3], b[4];
#pragma unroll
            for (int mt = 0; mt < 3; ++mt) a[mt] = ldb(mu + (size_t)mr[mt] * F + ko);
#pragma unroll
            for (int nt = 0; nt < 4; ++nt)
                b[nt] = ldb(WmixT + (size_t)(w * 64 + nt * 16 + lm) * F + ko);
#pragma unroll
            for (int mt = 0; mt < 3; ++mt)
#pragma unroll
                for (int nt = 0; nt < 4; ++nt)
                    acc[mt][nt] = __builtin_amdgcn_mfma_f32_16x16x32_bf16(a[mt], b[nt], acc[mt][nt], 0, 0, 0);
        }
#pragma unroll
        for (int mt = 0; mt < 3; ++mt)
#pragma unroll
            for (int nt = 0; nt < 4; ++nt)
#pragma unroll
                for (int r = 0; r < 4; ++r)
                    MM[mt * 16 + q4 * 4 + r][w * 64 + nt * 16 + lm] = (__bf16)acc[mt][nt][r];
    }
    __syncthreads();
    for (int idx = tid; idx < 16 * F; idx += 256) {
        int a = idx >> 7, f = idx & 127;
        int i = min(i0 + a, N - 1);
        float v0 = (float)MM[a * 3 + 0][f];
        float v1 = (float)MM[a * 3 + 1][f];
        float v2 = (float)MM[a * 3 + 2][f];
        CT[a][f] = (__bf16)q[(size_t)i * F + f];
        CT[a][F + f] = (__bf16)sqrtf(v0 * v0 + v1 * v1 + v2 * v2 + 1e-8f);
    }
    __syncthreads();
    {
        f32x4 c[2] = {};
        for (int kt = 0; kt < 8; ++kt) {
            int ko = kt * 32 + q4 * 8;
            bfrag a = ldsb(&CT[lm][ko]);
#pragma unroll
            for (int nt = 0; nt < 2; ++nt) {
                bfrag b = ldb(W1T + (size_t)(w * 32 + nt * 16 + lm) * 256 + ko);
                c[nt] = __builtin_amdgcn_mfma_f32_16x16x32_bf16(a, b, c[nt], 0, 0, 0);
            }
        }
#pragma unroll
        for (int nt = 0; nt < 2; ++nt) {
            int col = w * 32 + nt * 16 + lm;
            float bb = b1[col];
#pragma unroll
            for (int r = 0; r < 4; ++r) {
                float v = c[nt][r] + bb;
                HM[q4 * 4 + r][col] = (__bf16)(v / (1.0f + expf(-v)));
            }
        }
    }
    __syncthreads();
#pragma unroll
    for (int j = 0; j < 6; ++j) {
        int n0 = w * 96 + j * 16;
        f32x4 c = {};
        const bf16* bp = W2T + (size_t)(n0 + lm) * F;
        for (int kt = 0; kt < 4; ++kt) {
            int ko = kt * 32 + q4 * 8;
            bfrag a = ldsb(&HM[lm][ko]);
            bfrag b = ldb(bp + ko);
            c = __builtin_amdgcn_mfma_f32_16x16x32_bf16(a, b, c, 0, 0, 0);
        }
        int col = n0 + lm;
        float bb = b2[col];
#pragma unroll
        for (int r = 0; r < 4; ++r)
            Y[q4 * 4 + r][col] = (__bf16)(c[r] + bb);
    }
    __syncthreads();
    for (int idx = tid; idx < 16 * F; idx += 256) {
        int a = idx >> 7, f = idx & 127;
        int i = i0 + a;
        if (i >= N) continue;
        float V0 = (float)MM[a * 3 + 0][f], W0 = (float)MM[a * 3 + 0][F + f];
        float V1 = (float)MM[a * 3 + 1][f], W1v = (float)MM[a * 3 + 1][F + f];
        float V2 = (float)MM[a * 3 + 2][f], W2v = (float)MM[a * 3 + 2][F + f];
        float s = V0 * W0 + V1 * W1v + V2 * W2v;
        float yq = (float)Y[a][f], ym = (float)Y[a][F + f], ys = (float)Y[a][2 * F + f];
        q[(size_t)i * F + f] += yq + ys * s;
        size_t mb = (size_t)i * F3 + f;
        float nm0 = b2f(mu[mb]) + ym * W0;
        float nm1 = b2f(mu[mb + 128]) + ym * W1v;
        float nm2 = b2f(mu[mb + 256]) + ym * W2v;
        mu[mb]       = f2b(nm0);
        mu[mb + 128] = f2b(nm1);
        mu[mb + 256] = f2b(nm2);
        if (wp) {
            u16x4 pv;
            pv[0] = f2u(nm0);
            pv[1] = f2u(nm1);
            pv[2] = f2u(nm2);
            pv[3] = 0;
            *(u16x4*)(mup + (size_t)i * 512 + f * 4) = pv;
        }
    }
}

// ---------------- output: q ‖ mu, dtype per flag ----------------
__global__ void out_kernel(const float* __restrict__ q, const bf16* __restrict__ mu,
                           void* __restrict__ out, int N, const int* __restrict__ flag) {
    int idx = blockIdx.x * blockDim.x + threadIdx.x;
    int nq = N * F;
    int tot = nq + N * F3;
    if (idx >= tot) return;
    float v = (idx < nq) ? q[idx] : b2f(mu[idx - nq]);
    if (*flag) ((float*)out)[idx] = v;
    else       ((bf16*)out)[idx] = f2b(v);
}

extern "C" void kernel_launch(void* const* d_in, const int* in_sizes, int n_in,
                              void* d_out, int out_size, void* d_ws, size_t ws_size,
                              hipStream_t stream) {
    const int* z = (const int*)d_in[0];
    const int* idx_i = (const int*)d_in[2];
    const int* idx_j = (const int*)d_in[3];

    int N = in_sizes[0];
    int E = in_sizes[2];

    char* base = (char*)d_ws;
    size_t off = 0;
    auto alloc = [&](size_t bytes) -> void* {
        void* p = base + off;
        off += (bytes + 255) & ~(size_t)255;
        return p;
    };

    int* flag = (int*)alloc(4);
    float* pos_f = (float*)alloc((size_t)in_sizes[1] * 4);
    float* emb_f = (float*)alloc((size_t)in_sizes[4] * 4);
    float* fW_f = (float*)alloc((size_t)in_sizes[5] * 4);
    float* fb_f = (float*)alloc((size_t)in_sizes[6] * 4);
    float* iW1_f = (float*)alloc((size_t)in_sizes[7] * 4);
    float* ib1_f = (float*)alloc((size_t)in_sizes[8] * 4);
    float* iW2_f = (float*)alloc((size_t)in_sizes[9] * 4);
    float* ib2_f = (float*)alloc((size_t)in_sizes[10] * 4);
    float* mWmix_f = (float*)alloc((size_t)in_sizes[11] * 4);
    float* mW1_f = (float*)alloc((size_t)in_sizes[12] * 4);
    float* mb1_f = (float*)alloc((size_t)in_sizes[13] * 4);
    float* mW2_f = (float*)alloc((size_t)in_sizes[14] * 4);
    float* mb2_f = (float*)alloc((size_t)in_sizes[15] * 4);
    bf16* iW1T = (bf16*)alloc((size_t)NITER * F * F * 2);
    bf16* iW2T = (bf16*)alloc((size_t)NITER * F3 * F * 2);
    bf16* mWmixT = (bf16*)alloc((size_t)NITER * 2 * F * F * 2);
    bf16* mW1T = (bf16*)alloc((size_t)NITER * F * 2 * F * 2);
    bf16* mW2T = (bf16*)alloc((size_t)NITER * F3 * F * 2);
    float* fWTf = (float*)alloc((size_t)NITER * F3 * KP * 4);
    float* q = (float*)alloc((size_t)N * F * 4);
    bf16* mua = (bf16*)alloc((size_t)N * F3 * 2);
    bf16* mub = (bf16*)alloc((size_t)N * F3 * 2);
    bf16* xp = (bf16*)alloc((size_t)N * 512 * 2);
    bf16* mup = (bf16*)alloc((size_t)N * 512 * 2);
    float* phifc2 = (float*)alloc((size_t)(E + 16) * KP * 4);
    float* dir2 = (float*)alloc((size_t)(E + 16) * 4 * 4);
    int* jj2 = (int*)alloc((size_t)(E + 16) * 4);
    int* rank = (int*)alloc((size_t)E * 4);
    int* counts = (int*)alloc((size_t)N * 4);
    int* offs = (int*)alloc((size_t)(N + 1) * 4);

    hipMemsetAsync(flag, 0, 4, stream);
    detect_kernel<<<64, 256, 0, stream>>>((const unsigned short*)d_in[1], in_sizes[1], flag);

    {
        CvtArgs a;
        const int srcIdx[13] = {1, 4, 5, 6, 7, 8, 9, 10, 11, 12, 13, 14, 15};
        float* dsts[13] = {pos_f, emb_f, fW_f, fb_f, iW1_f, ib1_f, iW2_f, ib2_f,
                           mWmix_f, mW1_f, mb1_f, mW2_f, mb2_f};
        int cum = 0;
        a.end[0] = 0;
        for (int s = 0; s < 13; ++s) {
            a.src[s] = d_in[srcIdx[s]];
            a.dst[s] = dsts[s];
            cum += in_sizes[srcIdx[s]];
            a.end[s + 1] = cum;
        }
        cvt_all_kernel<<<(cum + 255) / 256, 256, 0, stream>>>(a, flag, cum);
    }

    {
        TpArgs a;
        const float* srcs[5] = {iW1_f, iW2_f, mWmix_f, mW1_f, mW2_f};
        bf16* dsts[5] = {iW1T, iW2T, mWmixT, mW1T, mW2T};
        int Ks[5] = {F, F, F, 2 * F, F};
        int Nns[5] = {F, F3, 2 * F, F, F3};
        int cum = 0;
        a.end[0] = 0;
        for (int s = 0; s < 5; ++s) {
            a.src[s] = srcs[s];
            a.dst[s] = dsts[s];
            a.K[s] = Ks[s];
            a.Nn[s] = Nns[s];
            cum += NITER * Ks[s] * Nns[s];
            a.end[s + 1] = cum;
        }
        tpose_all_kernel<<<(cum + 255) / 256, 256, 0, stream>>>(a, cum);
    }
    {
        int total = NITER * F3 * KP;
        fwt_kernel<<<(total + 255) / 256, 256, 0, stream>>>(fW_f, fb_f, fWTf, total);
    }

    // CSR build (rank needed by geom)
    hipMemsetAsync(counts, 0, (size_t)N * 4, stream);
    count_kernel<<<(E + 255) / 256, 256, 0, stream>>>(idx_i, counts, E);
    scan_kernel<<<1, 1024, 0, stream>>>(counts, offs, N);
    hipMemsetAsync(counts, 0, (size_t)N * 4, stream);
    fill_kernel<<<(E + 255) / 256, 256, 0, stream>>>(idx_i, offs, counts, rank, E);

    geom_kernel<<<(E + 255) / 256, 256, 0, stream>>>(pos_f, idx_i, idx_j, rank,
                                                     phifc2, dir2, jj2, E);
    embed_kernel<<<(N * F + 255) / 256, 256, 0, stream>>>(z, emb_f, q, N);
    hipMemsetAsync(mua, 0, (size_t)N * F3 * 2, stream);

    bf16* muin = mua;
    bf16* muout = mub;
    for (int t = 0; t < NITER; ++t) {
        atom_x_mfma<<<(N + 31) / 32, 256, 0, stream>>>(q, iW1T + (size_t)t * F * F, ib1_f + t * F,
                                                       iW2T + (size_t)t * F3 * F, ib2_f + t * F3,
                                                       xp, N);
        if (t == 0)
            edge_gather_v3<1><<<N, 128, 0, stream>>>(q, muin, xp, mup, phifc2, dir2, jj2,
                                                     fWTf + (size_t)t * F3 * KP, offs, muout, N);
        else
            edge_gather_v3<0><<<N, 128, 0, stream>>>(q, muin, xp, mup, phifc2, dir2, jj2,
                                                     fWTf + (size_t)t * F3 * KP, offs, muout, N);
        mix_mfma<<<(N + 15) / 16, 256, 0, stream>>>(q, muout, mWmixT + (size_t)t * 2 * F * F,
                                                    mW1T + (size_t)t * F * 2 * F, mb1_f + t * F,
                                                    mW2T + (size_t)t * F3 * F, mb2_f + t * F3,
                                                    mup, (t < NITER - 1) ? 1 : 0, N);
        bf16* tm = muin; muin = muout; muout = tm;
    }

    int tot = N * (F + F3);
    out_kernel<<<(tot + 255) / 256, 256, 0, stream>>>(q, muin, d_out, N, flag);
}

// Round 3
// 772.618 us; speedup vs baseline: 1.8844x; 1.1011x over previous
//
#include <hip/hip_runtime.h>
#include <hip/hip_bf16.h>

#define F 128
#define F3 384
#define NRBF 20
#define NITER 3
#define KP 24   // padded filter K: 0..19 phi*fc, 20 fc (bias slot), 21..23 zero

typedef __hip_bfloat16 bf16;
typedef __bf16 bfrag __attribute__((ext_vector_type(8)));
typedef float f32x4 __attribute__((ext_vector_type(4)));

__device__ __forceinline__ float b2f(bf16 v) { return __bfloat162float(v); }
__device__ __forceinline__ bf16 f2b(float v) { return __float2bfloat16(v); }
__device__ __forceinline__ bfrag ldb(const bf16* p) { return *(const bfrag*)p; }
__device__ __forceinline__ bfrag ldsb(const __bf16* p) { return *(const bfrag*)p; }
__device__ __forceinline__ bfrag cvtf(const float* p) {
    bfrag r;
#pragma unroll
    for (int j = 0; j < 8; ++j) r[j] = (__bf16)p[j];
    return r;
}

// ---------------- dtype detection: bf16 (flag=0) vs f32 (flag=1) ----------------
__global__ void detect_kernel(const unsigned short* __restrict__ raw, int n_u16,
                              int* __restrict__ flag) {
    int i = blockIdx.x * blockDim.x + threadIdx.x;
    int bad = 0;
    for (int k = i; k < n_u16; k += blockDim.x * gridDim.x) {
        unsigned e = (raw[k] >> 7) & 0xFFu;
        if (e >= 140u) bad = 1;
    }
    if (bad) atomicOr(flag, 1);
}

// ---------------- fused param convert: 13 arrays in one launch ----------------
struct CvtArgs {
    const void* src[13];
    float* dst[13];
    int end[14];
};
__global__ void cvt_all_kernel(CvtArgs a, const int* __restrict__ flag, int total) {
    int idx = blockIdx.x * blockDim.x + threadIdx.x;
    if (idx >= total) return;
    int s = 0;
    while (idx >= a.end[s + 1]) ++s;
    int local = idx - a.end[s];
    float v = (*flag) ? ((const float*)a.src[s])[local]
                      : b2f(((const bf16*)a.src[s])[local]);
    a.dst[s][local] = v;
}

// ---------------- fused transpose: 5 weight tensors, f32[NITER][K][Nn]->bf16[NITER][Nn][K] ----
struct TpArgs {
    const float* src[5];
    bf16* dst[5];
    int K[5];
    int Nn[5];
    int end[6];
};
__global__ void tpose_all_kernel(TpArgs a, int total) {
    int idx = blockIdx.x * blockDim.x + threadIdx.x;
    if (idx >= total) return;
    int s = 0;
    while (idx >= a.end[s + 1]) ++s;
    int local = idx - a.end[s];
    int K = a.K[s], Nn = a.Nn[s], slice = K * Nn;
    int t = local / slice, j = local - t * slice;
    int n = j / K, k = j - n * K;
    a.dst[s][local] = f2b(a.src[s][t * slice + k * Nn + n]);
}

// ---------------- fWTf: f32 [NITER][384][24], k=0..19 fW, k=20 fb, rest 0 ----------------
__global__ void fwt_kernel(const float* __restrict__ fW, const float* __restrict__ fb,
                           float* __restrict__ dst, int total) {
    int idx = blockIdx.x * blockDim.x + threadIdx.x;
    if (idx >= total) return;
    int k = idx % KP, rest = idx / KP;
    int n = rest % F3, t = rest / F3;
    float v = (k < NRBF) ? fW[k * (F3 * NITER) + t * F3 + n]
                         : (k == NRBF ? fb[t * F3 + n] : 0.0f);
    dst[idx] = v;
}

// ---------------- geometry -> CSR-slot-ordered edge data ----------------
// dir2[l] = {dx, dy, dz, bitcast(j)}  -- j folded into the pad word
__global__ void geom_kernel(const float* __restrict__ pos, const int* __restrict__ ii,
                            const int* __restrict__ jj, const int* __restrict__ rank,
                            float* __restrict__ phifc2, float* __restrict__ dir2, int E) {
    int e = blockIdx.x * blockDim.x + threadIdx.x;
    if (e >= E) return;
    int i = ii[e], j = jj[e], l = rank[e];
    float r[3];
#pragma unroll
    for (int d = 0; d < 3; ++d) {
        float v = pos[j * 3 + d] - pos[i * 3 + d];
        if (fabsf(v) < 1e-6f) v = 1e-6f;
        r[d] = v;
    }
    float dd = sqrtf(r[0] * r[0] + r[1] * r[1] + r[2] * r[2]);
    float inv = 1.0f / dd;
#pragma unroll
    for (int d = 0; d < 3; ++d) dir2[(size_t)l * 4 + d] = r[d] * inv;
    dir2[(size_t)l * 4 + 3] = __int_as_float(j);
    const float CUT = 5.0f;
    const float PI = 3.14159265358979323846f;
    float fc = (dd < CUT) ? 0.5f * (cosf(PI * dd / CUT) + 1.0f) : 0.0f;
    const float width = CUT / (NRBF - 1);
    const float coeff = -0.5f / (width * width);
    float* pr = phifc2 + (size_t)l * KP;
#pragma unroll
    for (int k = 0; k < NRBF; ++k) {
        float diff = dd - (float)k * width;
        pr[k] = expf(coeff * diff * diff) * fc;
    }
    pr[NRBF] = fc;
    pr[NRBF + 1] = 0.0f;
    pr[NRBF + 2] = 0.0f;
    pr[NRBF + 3] = 0.0f;
}

// ---------------- initial q from embedding ----------------
__global__ void embed_kernel(const int* __restrict__ z, const float* __restrict__ emb,
                             float* __restrict__ q, int N) {
    int idx = blockIdx.x * blockDim.x + threadIdx.x;
    if (idx >= N * F) return;
    int n = idx >> 7, f = idx & 127;
    q[idx] = emb[z[n] * F + f];
}

// ---------------- CSR build ----------------
__global__ void count_kernel(const int* __restrict__ ii, int* __restrict__ counts, int E) {
    int e = blockIdx.x * blockDim.x + threadIdx.x;
    if (e < E) atomicAdd(&counts[ii[e]], 1);
}

__global__ void scan_kernel(const int* __restrict__ counts, int* __restrict__ offs, int N) {
    __shared__ int cum[1024];
    int t = threadIdx.x;
    int chunk = (N + 1023) >> 10;
    int b = t * chunk;
    int e = b + chunk; if (e > N) e = N;
    int s = 0;
    for (int a = b; a < e; ++a) s += counts[a];
    cum[t] = s;
    __syncthreads();
    for (int o = 1; o < 1024; o <<= 1) {
        int u = (t >= o) ? cum[t - o] : 0;
        __syncthreads();
        cum[t] += u;
        __syncthreads();
    }
    int run = cum[t] - s;
    for (int a = b; a < e; ++a) { offs[a] = run; run += counts[a]; }
    if (t == 1023) offs[N] = cum[1023];
}

__global__ void fill_kernel(const int* __restrict__ ii, const int* __restrict__ offs,
                            int* __restrict__ cursor, int* __restrict__ rank, int E) {
    int e = blockIdx.x * blockDim.x + threadIdx.x;
    if (e >= E) return;
    int i = ii[e];
    int p = atomicAdd(&cursor[i], 1);
    rank[e] = offs[i] + p;
}

// ---------------- atom_x via MFMA: X = silu(Q@W1+b1)@W2+b2, 32 atoms/block ----------------
__global__ __launch_bounds__(256) void atom_x_mfma(
    const float* __restrict__ q, const bf16* __restrict__ W1T, const float* __restrict__ b1,
    const bf16* __restrict__ W2T, const float* __restrict__ b2, bf16* __restrict__ x, int N) {
    __shared__ __bf16 H[32][136];
    int tid = threadIdx.x;
    int w = tid >> 6, l = tid & 63;
    int lm = l & 15, q4 = l >> 4;
    int i0 = blockIdx.x * 32;
    f32x4 acc[2][2] = {};
    int r0 = min(i0 + lm, N - 1);
    int r1 = min(i0 + 16 + lm, N - 1);
    for (int kt = 0; kt < 4; ++kt) {
        int ko = kt * 32 + q4 * 8;
        bfrag a0 = cvtf(q + (size_t)r0 * F + ko);
        bfrag a1 = cvtf(q + (size_t)r1 * F + ko);
        bfrag b0 = ldb(W1T + (size_t)(w * 32 + lm) * F + ko);
        bfrag b1f = ldb(W1T + (size_t)(w * 32 + 16 + lm) * F + ko);
        acc[0][0] = __builtin_amdgcn_mfma_f32_16x16x32_bf16(a0, b0, acc[0][0], 0, 0, 0);
        acc[1][0] = __builtin_amdgcn_mfma_f32_16x16x32_bf16(a1, b0, acc[1][0], 0, 0, 0);
        acc[0][1] = __builtin_amdgcn_mfma_f32_16x16x32_bf16(a0, b1f, acc[0][1], 0, 0, 0);
        acc[1][1] = __builtin_amdgcn_mfma_f32_16x16x32_bf16(a1, b1f, acc[1][1], 0, 0, 0);
    }
#pragma unroll
    for (int nt = 0; nt < 2; ++nt) {
        int col = w * 32 + nt * 16 + lm;
        float bb = b1[col];
#pragma unroll
        for (int mt = 0; mt < 2; ++mt)
#pragma unroll
            for (int r = 0; r < 4; ++r) {
                float v = acc[mt][nt][r] + bb;
                H[mt * 16 + q4 * 4 + r][col] = (__bf16)(v / (1.0f + expf(-v)));
            }
    }
    __syncthreads();
#pragma unroll
    for (int j = 0; j < 6; ++j) {
        int n0 = w * 96 + j * 16;
        f32x4 c0 = {}, c1 = {};
        const bf16* bp = W2T + (size_t)(n0 + lm) * F;
        for (int kt = 0; kt < 4; ++kt) {
            int ko = kt * 32 + q4 * 8;
            bfrag a0 = ldsb(&H[lm][ko]);
            bfrag a1 = ldsb(&H[16 + lm][ko]);
            bfrag bf = ldb(bp + ko);
            c0 = __builtin_amdgcn_mfma_f32_16x16x32_bf16(a0, bf, c0, 0, 0, 0);
            c1 = __builtin_amdgcn_mfma_f32_16x16x32_bf16(a1, bf, c1, 0, 0, 0);
        }
        int col = n0 + lm;
        float bb = b2[col];
#pragma unroll
        for (int r = 0; r < 4; ++r) {
            int row0 = i0 + q4 * 4 + r;
            int row1 = row0 + 16;
            if (row0 < N) x[(size_t)row0 * F3 + col] = f2b(c0[r] + bb);
            if (row1 < N) x[(size_t)row1 * F3 + col] = f2b(c1[r] + bb);
        }
    }
}

// ---------------- edge gather: R0-proven structure + T0 byte cut + nt streams ----------------
// Model (R0/R2 evidence): dur ~= FETCH_SIZE / 1.85 TB/s (L2-miss-path bound).
// So: keep byte-minimal 768B row-major gathers (R0), cut mu bytes entirely at t=0,
// fold jj into dir2.w, and mark the one-pass phi/dir streams nontemporal so they
// don't evict gather lines from L2.
template<int T0>
__global__ __launch_bounds__(128, 2) void edge_gather_t(
    float* __restrict__ q, const bf16* __restrict__ mu_in, const bf16* __restrict__ x,
    const float* __restrict__ phifc2, const float* __restrict__ dir2,
    const float* __restrict__ fWTf,
    const int* __restrict__ offs, bf16* __restrict__ mu_out, int N) {
    int i = blockIdx.x;
    int f = threadIdx.x;
    float w0[21], w1[21], w2[21];
    {
        const f32x4* p0 = (const f32x4*)(fWTf + (size_t)f * KP);
        const f32x4* p1 = (const f32x4*)(fWTf + (size_t)(f + 128) * KP);
#pragma unroll
        for (int k = 0; k < 6; ++k) {
            f32x4 t0 = p0[k], t1 = p1[k];
#pragma unroll
            for (int r = 0; r < 4; ++r) {
                int kk = k * 4 + r;
                if (kk < 21) { w0[kk] = t0[r]; w1[kk] = t1[r]; }
            }
        }
        if constexpr (!T0) {
            const f32x4* p2 = (const f32x4*)(fWTf + (size_t)(f + 256) * KP);
#pragma unroll
            for (int k = 0; k < 6; ++k) {
                f32x4 t2 = p2[k];
#pragma unroll
                for (int r = 0; r < 4; ++r) {
                    int kk = k * 4 + r;
                    if (kk < 21) w2[kk] = t2[r];
                }
            }
        }
    }
    // pin: value becomes opaque to the compiler -> cannot rematerialize the load
#pragma unroll
    for (int k = 0; k < 21; ++k) {
        asm volatile("" : "+v"(w0[k]), "+v"(w1[k]));
        if constexpr (!T0) asm volatile("" : "+v"(w2[k]));
    }
    int beg = offs[i], end = offs[i + 1];
    float accq = 0.0f, am0 = 0.0f, am1 = 0.0f, am2 = 0.0f;
    for (int l = beg; l < end; ++l) {
        const f32x4* pr4 = (const f32x4*)(phifc2 + (size_t)l * KP);
        f32x4 p[6];
#pragma unroll
        for (int k = 0; k < 6; ++k) p[k] = __builtin_nontemporal_load(pr4 + k);
        float fl0 = 0.0f, fl1 = 0.0f, fl2 = 0.0f;
#pragma unroll
        for (int k = 0; k < 21; ++k) {
            float ph = p[k >> 2][k & 3];
            fl0 += ph * w0[k];
            fl1 += ph * w1[k];
            if constexpr (!T0) fl2 += ph * w2[k];
        }
        f32x4 dv = __builtin_nontemporal_load((const f32x4*)(dir2 + (size_t)l * 4));
        int j = __float_as_int(dv[3]);
        const bf16* xj = x + (size_t)j * F3;
        float dq = fl0 * b2f(xj[f]);
        float dR = fl1 * b2f(xj[f + 128]);
        accq += dq;
        if constexpr (!T0) {
            float dM = fl2 * b2f(xj[f + 256]);
            const bf16* muj = mu_in + (size_t)j * F3;
            am0 += dR * dv[0] + dM * b2f(muj[f]);
            am1 += dR * dv[1] + dM * b2f(muj[f + 128]);
            am2 += dR * dv[2] + dM * b2f(muj[f + 256]);
        } else {
            am0 += dR * dv[0];
            am1 += dR * dv[1];
            am2 += dR * dv[2];
        }
    }
    q[(size_t)i * F + f] += accq;
    size_t mb = (size_t)i * F3 + f;
    if constexpr (T0) {
        mu_out[mb]       = f2b(am0);
        mu_out[mb + 128] = f2b(am1);
        mu_out[mb + 256] = f2b(am2);
    } else {
        mu_out[mb]       = f2b(b2f(mu_in[mb]) + am0);
        mu_out[mb + 128] = f2b(b2f(mu_in[mb + 128]) + am1);
        mu_out[mb + 256] = f2b(b2f(mu_in[mb + 256]) + am2);
    }
}

// ---------------- mixing via MFMA, 16 atoms/block ----------------
__global__ __launch_bounds__(256) void mix_mfma(
    float* __restrict__ q, bf16* __restrict__ mu,
    const bf16* __restrict__ WmixT, const bf16* __restrict__ W1T, const float* __restrict__ b1,
    const bf16* __restrict__ W2T, const float* __restrict__ b2, int N) {
    __shared__ __bf16 MM[48][264];
    __shared__ __bf16 CT[16][264];
    __shared__ __bf16 HM[16][136];
    __shared__ __bf16 Y[16][392];
    int tid = threadIdx.x;
    int w = tid >> 6, l = tid & 63;
    int lm = l & 15, q4 = l >> 4;
    int i0 = blockIdx.x * 16;
    int rowsM = N * 3;
    {
        f32x4 acc[3][4] = {};
        int mr[3];
#pragma unroll
        for (int mt = 0; mt < 3; ++mt) mr[mt] = min(i0 * 3 + mt * 16 + lm, rowsM - 1);
        for (int kt = 0; kt < 4; ++kt) {
            int ko = kt * 32 + q4 * 8;
            bfrag a[3], b[4];
#pragma unroll
            for (int mt = 0; mt < 3; ++mt) a[mt] = ldb(mu + (size_t)mr[mt] * F + ko);
#pragma unroll
            for (int nt = 0; nt < 4; ++nt)
                b[nt] = ldb(WmixT + (size_t)(w * 64 + nt * 16 + lm) * F + ko);
#pragma unroll
            for (int mt = 0; mt < 3; ++mt)
#pragma unroll
                for (int nt = 0; nt < 4; ++nt)
                    acc[mt][nt] = __builtin_amdgcn_mfma_f32_16x16x32_bf16(a[mt], b[nt], acc[mt][nt], 0, 0, 0);
        }
#pragma unroll
        for (int mt = 0; mt < 3; ++mt)
#pragma unroll
            for (int nt = 0; nt < 4; ++nt)
#pragma unroll
                for (int r = 0; r < 4; ++r)
                    MM[mt * 16 + q4 * 4 + r][w * 64 + nt * 16 + lm] = (__bf16)acc[mt][nt][r];
    }
    __syncthreads();
    for (int idx = tid; idx < 16 * F; idx += 256) {
        int a = idx >> 7, f = idx & 127;
        int i = min(i0 + a, N - 1);
        float v0 = (float)MM[a * 3 + 0][f];
        float v1 = (float)MM[a * 3 + 1][f];
        float v2 = (float)MM[a * 3 + 2][f];
        CT[a][f] = (__bf16)q[(size_t)i * F + f];
        CT[a][F + f] = (__bf16)sqrtf(v0 * v0 + v1 * v1 + v2 * v2 + 1e-8f);
    }
    __syncthreads();
    {
        f32x4 c[2] = {};
        for (int kt = 0; kt < 8; ++kt) {
            int ko = kt * 32 + q4 * 8;
            bfrag a = ldsb(&CT[lm][ko]);
#pragma unroll
            for (int nt = 0; nt < 2; ++nt) {
                bfrag b = ldb(W1T + (size_t)(w * 32 + nt * 16 + lm) * 256 + ko);
                c[nt] = __builtin_amdgcn_mfma_f32_16x16x32_bf16(a, b, c[nt], 0, 0, 0);
            }
        }
#pragma unroll
        for (int nt = 0; nt < 2; ++nt) {
            int col = w * 32 + nt * 16 + lm;
            float bb = b1[col];
#pragma unroll
            for (int r = 0; r < 4; ++r) {
                float v = c[nt][r] + bb;
                HM[q4 * 4 + r][col] = (__bf16)(v / (1.0f + expf(-v)));
            }
        }
    }
    __syncthreads();
#pragma unroll
    for (int j = 0; j < 6; ++j) {
        int n0 = w * 96 + j * 16;
        f32x4 c = {};
        const bf16* bp = W2T + (size_t)(n0 + lm) * F;
        for (int kt = 0; kt < 4; ++kt) {
            int ko = kt * 32 + q4 * 8;
            bfrag a = ldsb(&HM[lm][ko]);
            bfrag b = ldb(bp + ko);
            c = __builtin_amdgcn_mfma_f32_16x16x32_bf16(a, b, c, 0, 0, 0);
        }
        int col = n0 + lm;
        float bb = b2[col];
#pragma unroll
        for (int r = 0; r < 4; ++r)
            Y[q4 * 4 + r][col] = (__bf16)(c[r] + bb);
    }
    __syncthreads();
    for (int idx = tid; idx < 16 * F; idx += 256) {
        int a = idx >> 7, f = idx & 127;
        int i = i0 + a;
        if (i >= N) continue;
        float V0 = (float)MM[a * 3 + 0][f], W0 = (float)MM[a * 3 + 0][F + f];
        float V1 = (float)MM[a * 3 + 1][f], W1v = (float)MM[a * 3 + 1][F + f];
        float V2 = (float)MM[a * 3 + 2][f], W2v = (float)MM[a * 3 + 2][F + f];
        float s = V0 * W0 + V1 * W1v + V2 * W2v;
        float yq = (float)Y[a][f], ym = (float)Y[a][F + f], ys = (float)Y[a][2 * F + f];
        q[(size_t)i * F + f] += yq + ys * s;
        size_t mb = (size_t)i * F3 + f;
        mu[mb]       = f2b(b2f(mu[mb]) + ym * W0);
        mu[mb + 128] = f2b(b2f(mu[mb + 128]) + ym * W1v);
        mu[mb + 256] = f2b(b2f(mu[mb + 256]) + ym * W2v);
    }
}

// ---------------- output: q ‖ mu, dtype per flag ----------------
__global__ void out_kernel(const float* __restrict__ q, const bf16* __restrict__ mu,
                           void* __restrict__ out, int N, const int* __restrict__ flag) {
    int idx = blockIdx.x * blockDim.x + threadIdx.x;
    int nq = N * F;
    int tot = nq + N * F3;
    if (idx >= tot) return;
    float v = (idx < nq) ? q[idx] : b2f(mu[idx - nq]);
    if (*flag) ((float*)out)[idx] = v;
    else       ((bf16*)out)[idx] = f2b(v);
}

extern "C" void kernel_launch(void* const* d_in, const int* in_sizes, int n_in,
                              void* d_out, int out_size, void* d_ws, size_t ws_size,
                              hipStream_t stream) {
    const int* z = (const int*)d_in[0];
    const int* idx_i = (const int*)d_in[2];
    const int* idx_j = (const int*)d_in[3];

    int N = in_sizes[0];
    int E = in_sizes[2];

    char* base = (char*)d_ws;
    size_t off = 0;
    auto alloc = [&](size_t bytes) -> void* {
        void* p = base + off;
        off += (bytes + 255) & ~(size_t)255;
        return p;
    };

    int* flag = (int*)alloc(4);
    float* pos_f = (float*)alloc((size_t)in_sizes[1] * 4);
    float* emb_f = (float*)alloc((size_t)in_sizes[4] * 4);
    float* fW_f = (float*)alloc((size_t)in_sizes[5] * 4);
    float* fb_f = (float*)alloc((size_t)in_sizes[6] * 4);
    float* iW1_f = (float*)alloc((size_t)in_sizes[7] * 4);
    float* ib1_f = (float*)alloc((size_t)in_sizes[8] * 4);
    float* iW2_f = (float*)alloc((size_t)in_sizes[9] * 4);
    float* ib2_f = (float*)alloc((size_t)in_sizes[10] * 4);
    float* mWmix_f = (float*)alloc((size_t)in_sizes[11] * 4);
    float* mW1_f = (float*)alloc((size_t)in_sizes[12] * 4);
    float* mb1_f = (float*)alloc((size_t)in_sizes[13] * 4);
    float* mW2_f = (float*)alloc((size_t)in_sizes[14] * 4);
    float* mb2_f = (float*)alloc((size_t)in_sizes[15] * 4);
    bf16* iW1T = (bf16*)alloc((size_t)NITER * F * F * 2);
    bf16* iW2T = (bf16*)alloc((size_t)NITER * F3 * F * 2);
    bf16* mWmixT = (bf16*)alloc((size_t)NITER * 2 * F * F * 2);
    bf16* mW1T = (bf16*)alloc((size_t)NITER * F * 2 * F * 2);
    bf16* mW2T = (bf16*)alloc((size_t)NITER * F3 * F * 2);
    float* fWTf = (float*)alloc((size_t)NITER * F3 * KP * 4);
    float* q = (float*)alloc((size_t)N * F * 4);
    bf16* mua = (bf16*)alloc((size_t)N * F3 * 2);
    bf16* mub = (bf16*)alloc((size_t)N * F3 * 2);
    bf16* xbuf = (bf16*)alloc((size_t)N * F3 * 2);
    float* phifc2 = (float*)alloc((size_t)(E + 16) * KP * 4);
    float* dir2 = (float*)alloc((size_t)(E + 16) * 4 * 4);
    int* rank = (int*)alloc((size_t)E * 4);
    int* counts = (int*)alloc((size_t)N * 4);
    int* offs = (int*)alloc((size_t)(N + 1) * 4);

    hipMemsetAsync(flag, 0, 4, stream);
    detect_kernel<<<64, 256, 0, stream>>>((const unsigned short*)d_in[1], in_sizes[1], flag);

    {
        CvtArgs a;
        const int srcIdx[13] = {1, 4, 5, 6, 7, 8, 9, 10, 11, 12, 13, 14, 15};
        float* dsts[13] = {pos_f, emb_f, fW_f, fb_f, iW1_f, ib1_f, iW2_f, ib2_f,
                           mWmix_f, mW1_f, mb1_f, mW2_f, mb2_f};
        int cum = 0;
        a.end[0] = 0;
        for (int s = 0; s < 13; ++s) {
            a.src[s] = d_in[srcIdx[s]];
            a.dst[s] = dsts[s];
            cum += in_sizes[srcIdx[s]];
            a.end[s + 1] = cum;
        }
        cvt_all_kernel<<<(cum + 255) / 256, 256, 0, stream>>>(a, flag, cum);
    }

    {
        TpArgs a;
        const float* srcs[5] = {iW1_f, iW2_f, mWmix_f, mW1_f, mW2_f};
        bf16* dsts[5] = {iW1T, iW2T, mWmixT, mW1T, mW2T};
        int Ks[5] = {F, F, F, 2 * F, F};
        int Nns[5] = {F, F3, 2 * F, F, F3};
        int cum = 0;
        a.end[0] = 0;
        for (int s = 0; s < 5; ++s) {
            a.src[s] = srcs[s];
            a.dst[s] = dsts[s];
            a.K[s] = Ks[s];
            a.Nn[s] = Nns[s];
            cum += NITER * Ks[s] * Nns[s];
            a.end[s + 1] = cum;
        }
        tpose_all_kernel<<<(cum + 255) / 256, 256, 0, stream>>>(a, cum);
    }
    {
        int total = NITER * F3 * KP;
        fwt_kernel<<<(total + 255) / 256, 256, 0, stream>>>(fW_f, fb_f, fWTf, total);
    }

    // CSR build (rank needed by geom)
    hipMemsetAsync(counts, 0, (size_t)N * 4, stream);
    count_kernel<<<(E + 255) / 256, 256, 0, stream>>>(idx_i, counts, E);
    scan_kernel<<<1, 1024, 0, stream>>>(counts, offs, N);
    hipMemsetAsync(counts, 0, (size_t)N * 4, stream);
    fill_kernel<<<(E + 255) / 256, 256, 0, stream>>>(idx_i, offs, counts, rank, E);

    geom_kernel<<<(E + 255) / 256, 256, 0, stream>>>(pos_f, idx_i, idx_j, rank,
                                                     phifc2, dir2, E);
    embed_kernel<<<(N * F + 255) / 256, 256, 0, stream>>>(z, emb_f, q, N);
    // no memset of mua needed: t=0 edge kernel (T0=1) never reads mu_in

    bf16* muin = mua;
    bf16* muout = mub;
    for (int t = 0; t < NITER; ++t) {
        atom_x_mfma<<<(N + 31) / 32, 256, 0, stream>>>(q, iW1T + (size_t)t * F * F, ib1_f + t * F,
                                                       iW2T + (size_t)t * F3 * F, ib2_f + t * F3,
                                                       xbuf, N);
        if (t == 0)
            edge_gather_t<1><<<N, 128, 0, stream>>>(q, muin, xbuf, phifc2, dir2,
                                                    fWTf + (size_t)t * F3 * KP, offs, muout, N);
        else
            edge_gather_t<0><<<N, 128, 0, stream>>>(q, muin, xbuf, phifc2, dir2,
                                                    fWTf + (size_t)t * F3 * KP, offs, muout, N);
        mix_mfma<<<(N + 15) / 16, 256, 0, stream>>>(q, muout, mWmixT + (size_t)t * 2 * F * F,
                                                    mW1T + (size_t)t * F * 2 * F, mb1_f + t * F,
                                                    mW2T + (size_t)t * F3 * F, mb2_f + t * F3, N);
        bf16* tm = muin; muin = muout; muout = tm;
    }

    int tot = N * (F + F3);
    out_kernel<<<(tot + 255) / 256, 256, 0, stream>>>(q, muin, d_out, N, flag);
}